// Round 1
// baseline (1806.665 us; speedup 1.0000x reference)
//
#include <hip/hip_runtime.h>

// lstm_seq2seq fused persistent kernel for MI355X (gfx950).
// B=16384 rows split across 256 WGs (64 rows each); each WG runs all 50
// recurrent steps locally (batch rows are independent -> no grid sync).
// gates = h @ W_hh^T done with v_mfma_f32_16x16x32_f16; h kept in LDS (f16),
// c in registers (f32). Encoder embedding folded into an effective K=2 input
// weight (W_ih_enc @ W_emb) computed by a prep kernel.

#define SEQ  20
#define TLEN 30

typedef _Float16 half8  __attribute__((ext_vector_type(8)));
typedef float    floatx4 __attribute__((ext_vector_type(4)));
typedef float    floatx2 __attribute__((ext_vector_type(2)));

// Persistent device-side scratch (rewritten every launch by prep kernel).
__device__ _Float16 g_whh_enc[1024 * 256];  // packed B layout (see prep)
__device__ _Float16 g_whh_dec[1024 * 256];  // packed B layout
__device__ _Float16 g_wout[512];            // W_out [2][256] as f16
__device__ float    g_weff[2048];           // (W_ih_enc @ W_emb) [1024][2]
__device__ float    g_beff[1024];           // W_ih_enc @ b_emb + b_enc

__device__ __forceinline__ float fast_sigmoid(float x) {
    float t = __expf(-x);
    return __builtin_amdgcn_rcpf(1.f + t);
}
__device__ __forceinline__ float fast_tanh(float x) {
    float t = __expf(-2.f * x);
    return 2.f * __builtin_amdgcn_rcpf(1.f + t) - 1.f;
}

// Packs W_hh[n][k] (1024x256) into per-(n-tile, k-step) blocks so that a
// wave's B-fragment load (16B/lane) is a contiguous, fully-coalesced 1KB:
//   dst[(n>>4)*4096 + kt*512 + q*128 + (n&15)*8 + j] = W[n*256 + kt*32 + q*8 + j]
__global__ void prep_kernel(const float* __restrict__ W_emb,
                            const float* __restrict__ b_emb,
                            const float* __restrict__ W_ih_enc,
                            const float* __restrict__ W_hh_enc,
                            const float* __restrict__ b_enc,
                            const float* __restrict__ W_hh_dec,
                            const float* __restrict__ W_out) {
    int gid = blockIdx.x * blockDim.x + threadIdx.x;
    int stride = gridDim.x * blockDim.x;
    for (int s = gid; s < 1024 * 256; s += stride) {
        int n = s >> 8, k = s & 255;
        int kt = k >> 5, q = (k >> 3) & 3, j = k & 7;
        int dst = (n >> 4) * 4096 + kt * 512 + q * 128 + (n & 15) * 8 + j;
        g_whh_enc[dst] = (_Float16)W_hh_enc[s];
        g_whh_dec[dst] = (_Float16)W_hh_dec[s];
    }
    if (gid < 512) g_wout[gid] = (_Float16)W_out[gid];
    if (gid < 1024) {
        float w0 = 0.f, w1 = 0.f, bb = b_enc[gid];
        const float* wr = &W_ih_enc[gid * 64];
        for (int e = 0; e < 64; e++) {
            float v = wr[e];
            w0 = fmaf(v, W_emb[2 * e],     w0);
            w1 = fmaf(v, W_emb[2 * e + 1], w1);
            bb = fmaf(v, b_emb[e],         bb);
        }
        g_weff[2 * gid] = w0; g_weff[2 * gid + 1] = w1; g_beff[gid] = bb;
    }
}

__global__ __launch_bounds__(512, 2) void lstm_fused(
        const float* __restrict__ x_input,    // [20][16384][2]
        const float* __restrict__ W_ih_dec,   // [1024][2]
        const float* __restrict__ b_dec,      // [1024]
        const float* __restrict__ b_out,      // [2]
        float* __restrict__ out)              // [30][16384][2]
{
    __shared__ __align__(16) _Float16 h_lds[64 * 264];  // rows padded 256->264
    __shared__ __align__(16) float    x_all[SEQ * 128];
    __shared__ __align__(16) float    xdec[128];
    __shared__ __align__(16) _Float16 wout_lds[512];

    const int tid = threadIdx.x;
    const int w   = tid >> 6;     // wave 0..7, owns hidden cols [32w,32w+32)
    const int L   = tid & 63;
    const int l16 = L & 15;
    const int q   = L >> 4;
    const long row0 = (long)blockIdx.x * 64;

    // stage this WG's x for all 20 encoder steps: x_all[t][2*m+j]
    for (int idx = tid; idx < SEQ * 128; idx += 512)
        x_all[idx] = x_input[(long)(idx >> 7) * 32768 + row0 * 2 + (idx & 127)];
    for (int idx = tid; idx < 64 * 264; idx += 512)
        h_lds[idx] = (_Float16)0.f;
    wout_lds[tid] = g_wout[tid];

    float bout_r = 0.f;
    if (L < 16) bout_r = b_out[L & 1];

    // A fragment (h) LDS offsets: A[m=l16][k=q*8+j]
    int a_off[4];
#pragma unroll
    for (int mt = 0; mt < 4; mt++) a_off[mt] = (16 * mt + l16) * 264 + q * 8;
    // B fragment offsets into packed weight layout; i = t2*4+g
    int b_off[8];
#pragma unroll
    for (int i = 0; i < 8; i++) {
        int t2 = i >> 2, g = i & 3;
        int tile = 16 * g + 2 * w + t2;    // (256*g + 32*w + 16*t2) / 16
        b_off[i] = tile * 4096 + q * 128 + l16 * 8;
    }

    // per-lane input-path constants for the 8 n-values this lane touches
    float cb[8], cw0[8], cw1[8];
#pragma unroll
    for (int i = 0; i < 8; i++) {
        int t2 = i >> 2, g = i & 3;
        int n = 256 * g + 32 * w + 16 * t2 + l16;
        cb[i]  = g_beff[n];
        cw0[i] = g_weff[2 * n];
        cw1[i] = g_weff[2 * n + 1];
    }

    floatx4 acc[4][8];        // [mt][t2*4+g], D tile: row=4q+r, col=l16
    float   c_st[4][2][4];    // cell state, same (m,hc) layout as acc regs
#pragma unroll
    for (int mt = 0; mt < 4; mt++)
#pragma unroll
        for (int t2 = 0; t2 < 2; t2++)
#pragma unroll
            for (int r = 0; r < 4; r++) c_st[mt][t2][r] = 0.f;

    __syncthreads();

    auto do_step = [&](const float* xsrc, const _Float16* __restrict__ Wb,
                       bool do_mm) {
        // gates init: bias + K=2 input contribution
#pragma unroll
        for (int mt = 0; mt < 4; mt++) {
            floatx2 xv[4];
#pragma unroll
            for (int r = 0; r < 4; r++)
                xv[r] = *(const floatx2*)&xsrc[2 * (16 * mt + 4 * q + r)];
#pragma unroll
            for (int i = 0; i < 8; i++) {
                floatx4 a;
#pragma unroll
                for (int r = 0; r < 4; r++)
                    a[r] = fmaf(xv[r][0], cw0[i], fmaf(xv[r][1], cw1[i], cb[i]));
                acc[mt][i] = a;
            }
        }
        // gates += h @ W_hh^T
        if (do_mm) {
#pragma unroll
            for (int kt = 0; kt < 8; kt++) {
                half8 A[4];
#pragma unroll
                for (int mt = 0; mt < 4; mt++)
                    A[mt] = *(const half8*)&h_lds[a_off[mt] + kt * 32];
                half8 B[8];
#pragma unroll
                for (int i = 0; i < 8; i++)
                    B[i] = *(const half8*)&Wb[b_off[i] + kt * 512];
#pragma unroll
                for (int i = 0; i < 8; i++)
#pragma unroll
                    for (int mt = 0; mt < 4; mt++)
                        acc[mt][i] = __builtin_amdgcn_mfma_f32_16x16x32_f16(
                            A[mt], B[i], acc[mt][i], 0, 0, 0);
            }
        }
        __syncthreads();   // all waves done reading h before overwrite
        // elementwise LSTM update; write h (f16) back to LDS
#pragma unroll
        for (int mt = 0; mt < 4; mt++)
#pragma unroll
            for (int t2 = 0; t2 < 2; t2++)
#pragma unroll
                for (int r = 0; r < 4; r++) {
                    float iv = fast_sigmoid(acc[mt][t2 * 4 + 0][r]);
                    float fv = fast_sigmoid(acc[mt][t2 * 4 + 1][r]);
                    float gv = fast_tanh   (acc[mt][t2 * 4 + 2][r]);
                    float ov = fast_sigmoid(acc[mt][t2 * 4 + 3][r]);
                    float cn = fmaf(fv, c_st[mt][t2][r], iv * gv);
                    c_st[mt][t2][r] = cn;
                    float hn = ov * fast_tanh(cn);
                    h_lds[(16 * mt + 4 * q + r) * 264 + 32 * w + 16 * t2 + l16] =
                        (_Float16)hn;
                }
        __syncthreads();   // h complete before next step / out-proj
    };

    // ===== encoder (step 0: h==0, skip the matmul) =====
#pragma unroll 1
    for (int ts = 0; ts < SEQ; ts++)
        do_step(&x_all[ts * 128], g_whh_enc, ts != 0);

    // swap to decoder input-path constants
#pragma unroll
    for (int i = 0; i < 8; i++) {
        int t2 = i >> 2, g = i & 3;
        int n = 256 * g + 32 * w + 16 * t2 + l16;
        cb[i]  = b_dec[n];
        cw0[i] = W_ih_dec[2 * n];
        cw1[i] = W_ih_dec[2 * n + 1];
    }

    // ===== autoregressive decoder =====
#pragma unroll 1
    for (int ds = 0; ds < TLEN; ds++) {
        do_step(ds == 0 ? &x_all[(SEQ - 1) * 128] : xdec, g_whh_dec, true);
        // out = h @ W_out^T + b_out  (N=2): wave w handles rows [8w, 8w+8)
        if (L < 16) {
            int m = 8 * w + (L >> 1), j = L & 1;
            float s = bout_r;
#pragma unroll
            for (int kk = 0; kk < 256; kk += 8) {
                half8 hv = *(const half8*)&h_lds[m * 264 + kk];
                half8 wv = *(const half8*)&wout_lds[j * 256 + kk];
#pragma unroll
                for (int u = 0; u < 8; u++)
                    s = fmaf((float)hv[u], (float)wv[u], s);
            }
            out[(long)ds * 32768 + (row0 + m) * 2 + j] = s;
            xdec[2 * m + j] = s;   // autoregressive feedback
        }
        __syncthreads();           // xdec visible to all waves next step
    }
}

extern "C" void kernel_launch(void* const* d_in, const int* in_sizes, int n_in,
                              void* d_out, int out_size, void* d_ws, size_t ws_size,
                              hipStream_t stream) {
    (void)in_sizes; (void)n_in; (void)d_ws; (void)ws_size; (void)out_size;
    const float* x      = (const float*)d_in[0];
    const float* W_emb  = (const float*)d_in[1];
    const float* b_emb  = (const float*)d_in[2];
    const float* W_ih_e = (const float*)d_in[3];
    const float* W_hh_e = (const float*)d_in[4];
    const float* b_enc  = (const float*)d_in[5];
    const float* W_ih_d = (const float*)d_in[6];
    const float* W_hh_d = (const float*)d_in[7];
    const float* b_dec  = (const float*)d_in[8];
    const float* W_out  = (const float*)d_in[9];
    const float* b_out  = (const float*)d_in[10];
    float* out = (float*)d_out;

    prep_kernel<<<512, 256, 0, stream>>>(W_emb, b_emb, W_ih_e, W_hh_e, b_enc,
                                         W_hh_d, W_out);
    lstm_fused<<<256, 512, 0, stream>>>(x, W_ih_d, b_dec, b_out, out);
}

// Round 2
// 743.512 us; speedup vs baseline: 2.4299x; 2.4299x over previous
//
#include <hip/hip_runtime.h>

// lstm_seq2seq fused persistent kernel for MI355X (gfx950), R2.
// B=16384 rows over 256 WGs (64 rows each, 1 WG/CU); all 50 recurrent steps
// run locally. Gates computed as one MFMA over augmented K=288:
//   A = [h(256) | x0 x1 1 | zeros]  (f16, packed A-fragment layout in LDS)
//   B = [W_hh   | w0 w1 b | zeros]  (f16, packed B layout in global, L2-resident)
// c-state in LDS (f32, per-thread chunks). h double-buffered -> 1 barrier/step
// (encoder), 2 (decoder, out-projection needs all-wave h).
// Register budget: acc 128 (AGPR) + ~75 arch < 256 @ launch_bounds(512,2).

#define SEQ  20
#define TLEN 30
#define KT   9            // 9 k-tiles of 32 (256 h + x0,x1,1 + pad)
#define HBUF (4 * KT * 512)   // 18432 halves per h buffer

typedef _Float16 half8   __attribute__((ext_vector_type(8)));
typedef float    floatx4 __attribute__((ext_vector_type(4)));

// Packed augmented weights, rewritten by prep_kernel every launch.
// layout: [(tile*9 + kt)*512 + q*128 + l16*8 + j], tile=n>>4, l16=n&15,
//         k = kt*32 + q*8 + j
__device__ _Float16 g_whh_enc[1024 * 288];
__device__ _Float16 g_whh_dec[1024 * 288];
__device__ _Float16 g_wout[512];          // W_out [2][256] as f16

__device__ __forceinline__ float fast_sigmoid(float x) {
    float t = __expf(-x);
    return __builtin_amdgcn_rcpf(1.f + t);
}
__device__ __forceinline__ float fast_tanh(float x) {
    float t = __expf(-2.f * x);
    return 2.f * __builtin_amdgcn_rcpf(1.f + t) - 1.f;
}

__global__ void prep_kernel(const float* __restrict__ W_emb,
                            const float* __restrict__ b_emb,
                            const float* __restrict__ W_ih_enc,
                            const float* __restrict__ W_hh_enc,
                            const float* __restrict__ b_enc,
                            const float* __restrict__ W_ih_dec,
                            const float* __restrict__ W_hh_dec,
                            const float* __restrict__ b_dec,
                            const float* __restrict__ W_out) {
    int gid = blockIdx.x * blockDim.x + threadIdx.x;
    int stride = gridDim.x * blockDim.x;
    for (int s = gid; s < 1024 * 288; s += stride) {
        int n = s / 288, k = s - n * 288;
        int tile = n >> 4, l16 = n & 15;
        int kt = k >> 5, q = (k >> 3) & 3, j = k & 7;
        int dst = (tile * 9 + kt) * 512 + q * 128 + l16 * 8 + j;
        float fe = 0.f, fd = 0.f;
        if (k < 256) {
            fe = W_hh_enc[n * 256 + k];
            fd = W_hh_dec[n * 256 + k];
        } else {
            int kp = k - 256;
            if (kp == 0) {
                fd = W_ih_dec[2 * n];
                const float* wr = &W_ih_enc[n * 64];
                for (int e = 0; e < 64; e++) fe = fmaf(wr[e], W_emb[2 * e], fe);
            } else if (kp == 1) {
                fd = W_ih_dec[2 * n + 1];
                const float* wr = &W_ih_enc[n * 64];
                for (int e = 0; e < 64; e++) fe = fmaf(wr[e], W_emb[2 * e + 1], fe);
            } else if (kp == 2) {
                fd = b_dec[n];
                fe = b_enc[n];
                const float* wr = &W_ih_enc[n * 64];
                for (int e = 0; e < 64; e++) fe = fmaf(wr[e], b_emb[e], fe);
            }
        }
        g_whh_enc[dst] = (_Float16)fe;
        g_whh_dec[dst] = (_Float16)fd;
    }
    if (gid < 512) g_wout[gid] = (_Float16)W_out[gid];
}

__global__ __launch_bounds__(512, 2) void lstm_fused(
        const float* __restrict__ x_input,    // [20][16384][2]
        const float* __restrict__ b_out,      // [2]
        float* __restrict__ out)              // [30][16384][2]
{
    // h packed A-layout: [buf][mt(4)][kt(9)][q(4)][l16(16)][j(8)] halves
    __shared__ __align__(16) _Float16 h_pack[2][HBUF];     // 73728 B
    __shared__ __align__(16) float    c_lds[16384];        // 65536 B, per-thread chunks
    __shared__ __align__(16) _Float16 wout_lds[512];       // 1024 B

    const int tid = threadIdx.x;
    const int w   = tid >> 6;       // wave 0..7, owns hidden cols [32w,32w+32)
    const int L   = tid & 63;
    const int l16 = L & 15;
    const int q   = L >> 4;
    const long row0 = (long)blockIdx.x * 64;

    // ---- prefill: zero h bufs + c, set the "1" column, stage x(0) ----
    {
        int* hz = (int*)&h_pack[0][0];
        for (int idx = tid; idx < HBUF; idx += 512) hz[idx] = 0;   // both bufs (2*HBUF halves = HBUF ints)
        for (int idx = tid; idx < 16384; idx += 512) c_lds[idx] = 0.f;
        if (tid < 128) {
            int buf = tid >> 6, row = tid & 63;
            h_pack[buf][((row >> 4) * 9 + 8) * 512 + (row & 15) * 8 + 2] = (_Float16)1.f;
        }
        if (tid < 128) {
            int row = tid >> 1, jj = tid & 1;
            h_pack[0][((row >> 4) * 9 + 8) * 512 + (row & 15) * 8 + jj] =
                (_Float16)x_input[(row0 + row) * 2 + jj];
        }
        wout_lds[tid] = g_wout[tid];
    }

    float bout_r = 0.f;
    if (L < 16) bout_r = b_out[L & 1];

    const int aoff = q * 128 + l16 * 8;   // lane offset within a 512-half block
    int b_off[8];                          // halves into packed weights; i = t2*4+g
#pragma unroll
    for (int i = 0; i < 8; i++) {
        int t2 = i >> 2, g = i & 3;
        int tile = 16 * g + 2 * w + t2;
        b_off[i] = tile * 4608 + aoff;     // 4608 = 9*512
    }

    floatx4 acc[4][8];   // [mt][t2*4+g]; D: row=16mt+4q+r (batch), col=l16 (gate n)

    __syncthreads();

    int cur = 0;
#pragma unroll 1
    for (int t = 0; t < SEQ + TLEN; t++) {
        const bool dec = (t >= SEQ);
        const _Float16* __restrict__ Wb = dec ? g_whh_dec : g_whh_enc;
        const _Float16* hp = h_pack[cur];
        _Float16* hn = h_pack[cur ^ 1];

        // ---- gates = [h|x|1] @ Waug^T  (zero acc, 9 k-tiles) ----
#pragma unroll
        for (int mt = 0; mt < 4; mt++)
#pragma unroll
            for (int i = 0; i < 8; i++) acc[mt][i] = (floatx4)(0.f);

#pragma unroll
        for (int kt = 0; kt < KT; kt++) {
            half8 A[4];
#pragma unroll
            for (int mt = 0; mt < 4; mt++)
                A[mt] = *(const half8*)&hp[(mt * 9 + kt) * 512 + aoff];
            half8 B[8];
#pragma unroll
            for (int i = 0; i < 8; i++)
                B[i] = *(const half8*)&Wb[b_off[i] + kt * 512];
#pragma unroll
            for (int i = 0; i < 8; i++)
#pragma unroll
                for (int mt = 0; mt < 4; mt++)
                    acc[mt][i] = __builtin_amdgcn_mfma_f32_16x16x32_f16(
                        A[mt], B[i], acc[mt][i], 0, 0, 0);
        }

        // issue next-step x load early (encoder phase; t==19 re-feeds x(19))
        float xval = 0.f;
        if (!dec && tid < 128) {
            int src_t = (t + 1 < SEQ) ? t + 1 : SEQ - 1;
            xval = x_input[(long)src_t * 32768 + (row0 + (tid >> 1)) * 2 + (tid & 1)];
        }

        // ---- elementwise LSTM update; h (f16) -> nxt buffer, kt block = w ----
#pragma unroll
        for (int mt = 0; mt < 4; mt++)
#pragma unroll
            for (int t2 = 0; t2 < 2; t2++) {
                int ci = ((w * 8 + mt * 2 + t2) * 64 + L) * 4;
                floatx4 c4 = *(floatx4*)&c_lds[ci];
                _Float16* hw = &hn[(mt * 9 + w) * 512 +
                                   (2 * t2 + (l16 >> 3)) * 128 + (l16 & 7)];
#pragma unroll
                for (int r = 0; r < 4; r++) {
                    float iv = fast_sigmoid(acc[mt][t2 * 4 + 0][r]);
                    float fv = fast_sigmoid(acc[mt][t2 * 4 + 1][r]);
                    float gv = fast_tanh   (acc[mt][t2 * 4 + 2][r]);
                    float ov = fast_sigmoid(acc[mt][t2 * 4 + 3][r]);
                    float cn = fmaf(fv, c4[r], iv * gv);
                    c4[r] = cn;
                    hw[(4 * q + r) * 8] = (_Float16)(ov * fast_tanh(cn));
                }
                *(floatx4*)&c_lds[ci] = c4;
            }

        if (!dec && tid < 128) {
            int row = tid >> 1, jj = tid & 1;
            hn[((row >> 4) * 9 + 8) * 512 + (row & 15) * 8 + jj] = (_Float16)xval;
        }

        __syncthreads();   // nxt complete (h everywhere; x for encoder)

        if (dec) {
            // out = h_new @ W_out^T + b_out; h_new lives in nxt (all waves' cols)
            if (L < 16) {
                int m = 8 * w + (L >> 1), jj = L & 1;
                int mtm = m >> 4, lm = (m & 15) * 8;
                float s = bout_r;
#pragma unroll
                for (int kt = 0; kt < 8; kt++)
#pragma unroll
                    for (int qq = 0; qq < 4; qq++) {
                        half8 hv = *(const half8*)&hn[(mtm * 9 + kt) * 512 + qq * 128 + lm];
                        half8 wv = *(const half8*)&wout_lds[jj * 256 + kt * 32 + qq * 8];
#pragma unroll
                        for (int u = 0; u < 8; u++)
                            s = fmaf((float)hv[u], (float)wv[u], s);
                    }
                out[(long)(t - SEQ) * 32768 + (row0 + m) * 2 + jj] = s;
                // autoregressive feedback -> x slot of nxt
                hn[(mtm * 9 + 8) * 512 + (m & 15) * 8 + jj] = (_Float16)s;
            }
            __syncthreads();   // x slot visible before next step's MFMA
        }

        cur ^= 1;
    }
}

extern "C" void kernel_launch(void* const* d_in, const int* in_sizes, int n_in,
                              void* d_out, int out_size, void* d_ws, size_t ws_size,
                              hipStream_t stream) {
    (void)in_sizes; (void)n_in; (void)d_ws; (void)ws_size; (void)out_size;
    const float* x      = (const float*)d_in[0];
    const float* W_emb  = (const float*)d_in[1];
    const float* b_emb  = (const float*)d_in[2];
    const float* W_ih_e = (const float*)d_in[3];
    const float* W_hh_e = (const float*)d_in[4];
    const float* b_enc  = (const float*)d_in[5];
    const float* W_ih_d = (const float*)d_in[6];
    const float* W_hh_d = (const float*)d_in[7];
    const float* b_dec  = (const float*)d_in[8];
    const float* W_out  = (const float*)d_in[9];
    const float* b_out  = (const float*)d_in[10];
    float* outp = (float*)d_out;

    prep_kernel<<<512, 256, 0, stream>>>(W_emb, b_emb, W_ih_e, W_hh_e, b_enc,
                                         W_ih_d, W_hh_d, b_dec, W_out);
    lstm_fused<<<256, 512, 0, stream>>>(x, b_out, outp);
}